// Round 1
// baseline (299.512 us; speedup 1.0000x reference)
//
#include <hip/hip_runtime.h>
#include <hip/hip_bf16.h>

// SDPA causal, B=2 H=16 S=2048 D=64, scale=8. Outputs: attn(f32, B*H*S*S) ++ out(f32, B*H*S*D).
#define S_LEN 2048
#define D_HEAD 64

typedef __attribute__((ext_vector_type(8))) short short8;   // 8 bf16 (4 VGPR) MFMA A/B frag
typedef __attribute__((ext_vector_type(4))) float f32x4;    // MFMA C/D frag

__device__ __forceinline__ unsigned short f2b(float f) {    // fp32 -> bf16 (RNE)
  unsigned int u = __float_as_uint(f);
  u += 0x7fffu + ((u >> 16) & 1u);
  return (unsigned short)(u >> 16);
}

__global__ __launch_bounds__(256) void sdpa_causal_kernel(
    const float* __restrict__ Qg, const float* __restrict__ Kg,
    const float* __restrict__ Vg, float* __restrict__ attn,
    float* __restrict__ outp) {
  // XCD swizzle: 1024 blocks, hw%8 ~ XCD -> 4 consecutive bh per XCD (K/V L2-resident)
  const int hw = blockIdx.x;
  const int logical = (hw & 7) * 128 + (hw >> 3);
  const int bh = logical >> 5;   // 0..31
  const int qt = logical & 31;   // 0..31
  const int q0 = qt << 6;
  const int kmax = q0 + 64;      // exclusive causal column limit for this block

  const int tid  = threadIdx.x;
  const int wave = tid >> 6;
  const int lane = tid & 63;
  const int g = lane >> 4;       // 0..3
  const int m = lane & 15;       // 0..15
  const int swzm = (m & 7) << 4; // XOR-swizzle term for row==m reads

  // LDS: all XOR-swizzled by ((row&7)<<4) on the byte offset (G4 fix for 128B-stride conflicts)
  __shared__ __align__(16) unsigned short Kl[32 * 64];     // K tile [s][d] bf16
  __shared__ __align__(16) unsigned short Vt[64 * 32];     // V tile transposed [d][s] bf16
  __shared__ __align__(16) unsigned short Pl[4][16 * 32];  // per-wave P tile [q][k] bf16
  char* const KlB = (char*)Kl;
  char* const VtB = (char*)Vt;
  char* const PlB = (char*)(&Pl[wave][0]);

  const size_t bhSD = (size_t)bh * S_LEN * D_HEAD;
  const size_t bhSS = (size_t)bh * S_LEN * S_LEN;

  const int qwrow = q0 + wave * 16;   // wave's first q row
  const int qwend = qwrow + 16;       // exclusive
  const int qbase = qwrow + g * 4;    // q row of C-frag reg 0 (row = 4g+reg, col = m)

  // ---- Q A-fragments, pre-scaled by log2(e)/8 (folds softmax scale + exp->exp2) ----
  const float SCL = 0.18033688011112042f;
  short8 aq0, aq1;  // d-chunks [0,32) and [32,64); A layout: row=lane&15, k=8*(lane>>4)+i
  {
    const float* qp = Qg + bhSD + (size_t)(qwrow + m) * D_HEAD + g * 8;
    float4 x0 = *(const float4*)(qp);
    float4 x1 = *(const float4*)(qp + 4);
    float4 y0 = *(const float4*)(qp + 32);
    float4 y1 = *(const float4*)(qp + 36);
    aq0[0]=(short)f2b(x0.x*SCL); aq0[1]=(short)f2b(x0.y*SCL);
    aq0[2]=(short)f2b(x0.z*SCL); aq0[3]=(short)f2b(x0.w*SCL);
    aq0[4]=(short)f2b(x1.x*SCL); aq0[5]=(short)f2b(x1.y*SCL);
    aq0[6]=(short)f2b(x1.z*SCL); aq0[7]=(short)f2b(x1.w*SCL);
    aq1[0]=(short)f2b(y0.x*SCL); aq1[1]=(short)f2b(y0.y*SCL);
    aq1[2]=(short)f2b(y0.z*SCL); aq1[3]=(short)f2b(y0.w*SCL);
    aq1[4]=(short)f2b(y1.x*SCL); aq1[5]=(short)f2b(y1.y*SCL);
    aq1[6]=(short)f2b(y1.z*SCL); aq1[7]=(short)f2b(y1.w*SCL);
  }

  // ================= Phase 1: row sums of exp =================
  float rs0 = 0.f, rs1 = 0.f, rs2 = 0.f, rs3 = 0.f;
  for (int kc = 0; kc < kmax; kc += 32) {
    __syncthreads();
    #pragma unroll
    for (int j = 0; j < 2; ++j) {            // stage K[kc..kc+32)x[0..64) -> bf16 LDS
      int f = tid + j * 256;
      int s = f >> 4;
      int d4 = (f & 15) << 2;
      float4 kv = *(const float4*)(Kg + bhSD + (size_t)(kc + s) * D_HEAD + d4);
      ushort4 kb;
      kb.x = f2b(kv.x); kb.y = f2b(kv.y); kb.z = f2b(kv.z); kb.w = f2b(kv.w);
      int off = ((((s << 6) + d4) << 1)) ^ ((s & 7) << 4);
      *(ushort4*)(KlB + off) = kb;
    }
    __syncthreads();
    if (kc < qwend) {
      #pragma unroll
      for (int t = 0; t < 2; ++t) {
        f32x4 acc = {0.f, 0.f, 0.f, 0.f};
        int base = (t * 16 + m) << 6;  // col*64, B layout: col=lane&15, k=8*(lane>>4)+i
        int off0 = ((base + g * 8) << 1) ^ swzm;
        int off1 = ((base + 32 + g * 8) << 1) ^ swzm;
        short8 b0 = *(const short8*)(KlB + off0);
        short8 b1 = *(const short8*)(KlB + off1);
        acc = __builtin_amdgcn_mfma_f32_16x16x32_bf16(aq0, b0, acc, 0, 0, 0);
        acc = __builtin_amdgcn_mfma_f32_16x16x32_bf16(aq1, b1, acc, 0, 0, 0);
        int kcol = kc + t * 16 + m;
        rs0 += (kcol <= qbase + 0) ? exp2f(acc[0]) : 0.f;
        rs1 += (kcol <= qbase + 1) ? exp2f(acc[1]) : 0.f;
        rs2 += (kcol <= qbase + 2) ? exp2f(acc[2]) : 0.f;
        rs3 += (kcol <= qbase + 3) ? exp2f(acc[3]) : 0.f;
      }
    }
  }
  #pragma unroll
  for (int sft = 1; sft < 16; sft <<= 1) {  // butterfly over the 16 lanes sharing g
    rs0 += __shfl_xor(rs0, sft, 64);
    rs1 += __shfl_xor(rs1, sft, 64);
    rs2 += __shfl_xor(rs2, sft, 64);
    rs3 += __shfl_xor(rs3, sft, 64);
  }
  const float ri0 = 1.f / rs0, ri1 = 1.f / rs1, ri2 = 1.f / rs2, ri3 = 1.f / rs3;

  // ================= Phase 2: recompute, write attn, accumulate O =================
  f32x4 o0 = {0.f,0.f,0.f,0.f}, o1 = {0.f,0.f,0.f,0.f};
  f32x4 o2 = {0.f,0.f,0.f,0.f}, o3 = {0.f,0.f,0.f,0.f};

  for (int kc = 0; kc < kmax; kc += 32) {
    __syncthreads();
    #pragma unroll
    for (int j = 0; j < 2; ++j) {            // stage K and V^T
      int f = tid + j * 256;
      int s = f >> 4;
      int d4 = (f & 15) << 2;
      float4 kv = *(const float4*)(Kg + bhSD + (size_t)(kc + s) * D_HEAD + d4);
      ushort4 kb;
      kb.x = f2b(kv.x); kb.y = f2b(kv.y); kb.z = f2b(kv.z); kb.w = f2b(kv.w);
      int off = ((((s << 6) + d4) << 1)) ^ ((s & 7) << 4);
      *(ushort4*)(KlB + off) = kb;
      float4 vv = *(const float4*)(Vg + bhSD + (size_t)(kc + s) * D_HEAD + d4);
      unsigned short vb0 = f2b(vv.x), vb1 = f2b(vv.y), vb2 = f2b(vv.z), vb3 = f2b(vv.w);
      int d0 = d4;
      *(unsigned short*)(VtB + (((((d0+0) << 5) + s) << 1) ^ (((d0+0) & 7) << 4))) = vb0;
      *(unsigned short*)(VtB + (((((d0+1) << 5) + s) << 1) ^ (((d0+1) & 7) << 4))) = vb1;
      *(unsigned short*)(VtB + (((((d0+2) << 5) + s) << 1) ^ (((d0+2) & 7) << 4))) = vb2;
      *(unsigned short*)(VtB + (((((d0+3) << 5) + s) << 1) ^ (((d0+3) & 7) << 4))) = vb3;
    }
    __syncthreads();
    if (kc < qwend) {
      #pragma unroll
      for (int t = 0; t < 2; ++t) {
        f32x4 acc = {0.f, 0.f, 0.f, 0.f};
        int base = (t * 16 + m) << 6;
        int off0 = ((base + g * 8) << 1) ^ swzm;
        int off1 = ((base + 32 + g * 8) << 1) ^ swzm;
        short8 b0 = *(const short8*)(KlB + off0);
        short8 b1 = *(const short8*)(KlB + off1);
        acc = __builtin_amdgcn_mfma_f32_16x16x32_bf16(aq0, b0, acc, 0, 0, 0);
        acc = __builtin_amdgcn_mfma_f32_16x16x32_bf16(aq1, b1, acc, 0, 0, 0);
        int kcol = kc + t * 16 + m;
        float p0 = (kcol <= qbase + 0) ? exp2f(acc[0]) * ri0 : 0.f;
        float p1 = (kcol <= qbase + 1) ? exp2f(acc[1]) * ri1 : 0.f;
        float p2 = (kcol <= qbase + 2) ? exp2f(acc[2]) * ri2 : 0.f;
        float p3 = (kcol <= qbase + 3) ? exp2f(acc[3]) * ri3 : 0.f;
        attn[bhSS + (size_t)(qbase + 0) * S_LEN + kcol] = p0;
        attn[bhSS + (size_t)(qbase + 1) * S_LEN + kcol] = p1;
        attn[bhSS + (size_t)(qbase + 2) * S_LEN + kcol] = p2;
        attn[bhSS + (size_t)(qbase + 3) * S_LEN + kcol] = p3;
        // P -> per-wave LDS (C-layout scatter), swizzled
        int r0 = g * 4;
        int c = t * 16 + m;
        *(unsigned short*)(PlB + (((((r0+0) << 5) + c) << 1) ^ (((r0+0) & 7) << 4))) = f2b(p0);
        *(unsigned short*)(PlB + (((((r0+1) << 5) + c) << 1) ^ (((r0+1) & 7) << 4))) = f2b(p1);
        *(unsigned short*)(PlB + (((((r0+2) << 5) + c) << 1) ^ (((r0+2) & 7) << 4))) = f2b(p2);
        *(unsigned short*)(PlB + (((((r0+3) << 5) + c) << 1) ^ (((r0+3) & 7) << 4))) = f2b(p3);
      }
      // PV: A = P (row=m, k=8g+i), B = V^T reads (col=d=16dc+m, k=8g+i)
      int aoff = (((m << 5) + g * 8) << 1) ^ swzm;
      short8 apf = *(const short8*)(PlB + aoff);
      {
        int voff = ((((0 * 16 + m) << 5) + g * 8) << 1) ^ swzm;
        short8 bv = *(const short8*)(VtB + voff);
        o0 = __builtin_amdgcn_mfma_f32_16x16x32_bf16(apf, bv, o0, 0, 0, 0);
      }
      {
        int voff = ((((1 * 16 + m) << 5) + g * 8) << 1) ^ swzm;
        short8 bv = *(const short8*)(VtB + voff);
        o1 = __builtin_amdgcn_mfma_f32_16x16x32_bf16(apf, bv, o1, 0, 0, 0);
      }
      {
        int voff = ((((2 * 16 + m) << 5) + g * 8) << 1) ^ swzm;
        short8 bv = *(const short8*)(VtB + voff);
        o2 = __builtin_amdgcn_mfma_f32_16x16x32_bf16(apf, bv, o2, 0, 0, 0);
      }
      {
        int voff = ((((3 * 16 + m) << 5) + g * 8) << 1) ^ swzm;
        short8 bv = *(const short8*)(VtB + voff);
        o3 = __builtin_amdgcn_mfma_f32_16x16x32_bf16(apf, bv, o3, 0, 0, 0);
      }
    } else {
      // wave's 16x32 tile fully masked: write zeros
      #pragma unroll
      for (int t = 0; t < 2; ++t) {
        int kcol = kc + t * 16 + m;
        attn[bhSS + (size_t)(qbase + 0) * S_LEN + kcol] = 0.f;
        attn[bhSS + (size_t)(qbase + 1) * S_LEN + kcol] = 0.f;
        attn[bhSS + (size_t)(qbase + 2) * S_LEN + kcol] = 0.f;
        attn[bhSS + (size_t)(qbase + 3) * S_LEN + kcol] = 0.f;
      }
    }
  }

  // ---- store O (16 q-rows x 64 d per wave) ----
  #pragma unroll
  for (int reg = 0; reg < 4; ++reg) {
    size_t rb = bhSD + (size_t)(qbase + reg) * D_HEAD + m;
    outp[rb +  0] = o0[reg];
    outp[rb + 16] = o1[reg];
    outp[rb + 32] = o2[reg];
    outp[rb + 48] = o3[reg];
  }

  // ---- zero-fill fully-masked columns [kmax, S) for the block's 64 rows ----
  const int ncols = S_LEN - kmax;
  if (ncols > 0) {
    const float4 z = {0.f, 0.f, 0.f, 0.f};
    const int nvec = ncols >> 2;
    for (int r = 0; r < 64; ++r) {
      float4* rp = (float4*)(attn + bhSS + (size_t)(q0 + r) * S_LEN + kmax);
      for (int i = tid; i < nvec; i += 256) rp[i] = z;
    }
  }
}

extern "C" void kernel_launch(void* const* d_in, const int* in_sizes, int n_in,
                              void* d_out, int out_size, void* d_ws, size_t ws_size,
                              hipStream_t stream) {
  (void)in_sizes; (void)n_in; (void)d_ws; (void)ws_size; (void)out_size;
  const float* q = (const float*)d_in[0];
  const float* k = (const float*)d_in[1];
  const float* v = (const float*)d_in[2];
  // d_in[3] (mask) ignored: causal mask is recomputed from indices.
  float* attn = (float*)d_out;
  float* outp = attn + (size_t)2 * 16 * 2048 * 2048;
  dim3 grid(2 * 16 * (2048 / 64));  // 1024 blocks
  dim3 block(256);
  sdpa_causal_kernel<<<grid, block, 0, stream>>>(q, k, v, attn, outp);
}

// Round 2
// 221.592 us; speedup vs baseline: 1.3516x; 1.3516x over previous
//
#include <hip/hip_runtime.h>
#include <hip/hip_bf16.h>

// SDPA causal, B=2 H=16 S=2048 D=64, scale=8. Outputs: attn(f32) ++ out(f32).
// R2: paired strips (qt, 31-qt) per block for exact load balance; KC=64;
// double-buffered LDS with async-split staging (1 barrier/iter); V^T swizzle fix.
#define S_LEN 2048
#define D_HEAD 64

typedef __attribute__((ext_vector_type(8))) short short8;   // 8 bf16 MFMA A/B frag
typedef __attribute__((ext_vector_type(4))) float f32x4;    // MFMA C/D frag

__device__ __forceinline__ unsigned short f2b(float f) {    // fp32 -> bf16 (RNE)
  unsigned int u = __float_as_uint(f);
  u += 0x7fffu + ((u >> 16) & 1u);
  return (unsigned short)(u >> 16);
}

__global__ __launch_bounds__(256) void sdpa_causal_kernel(
    const float* __restrict__ Qg, const float* __restrict__ Kg,
    const float* __restrict__ Vg, float* __restrict__ attn,
    float* __restrict__ outp) {
  const int bh = blockIdx.x >> 4;   // 0..31
  const int pi = blockIdx.x & 15;   // 0..15 -> strips qt=pi and qt=31-pi

  const int tid  = threadIdx.x;
  const int wave = tid >> 6;
  const int lane = tid & 63;
  const int g = lane >> 4;          // 0..3
  const int m = lane & 15;          // 0..15
  const int swzK = (m & 7) << 4;    // row-swizzle for K/P reads (row == m mod 8)

  __shared__ __align__(16) unsigned short Kl[2][64 * 64];  // K tile [s][d], dbuf
  __shared__ __align__(16) unsigned short Vt[2][64 * 64];  // V^T tile [d][s], dbuf
  __shared__ __align__(16) unsigned short Pl[4][16 * 64];  // per-wave P [q][k]
  char* const PB = (char*)(&Pl[wave][0]);

  const size_t bhSD = (size_t)bh * (S_LEN * D_HEAD);
  const size_t bhSS = (size_t)bh * ((size_t)S_LEN * S_LEN);

  // staging coords: thread covers 4 (s, d4) cells of a 64x64 tile
  int ss[4], dd[4], koff[4];
  #pragma unroll
  for (int j = 0; j < 4; ++j) {
    int f = tid + j * 256;
    ss[j] = f >> 4;             // 0..63 (k-row within tile)
    dd[j] = (f & 15) << 2;      // 0..60 (d col, x4)
    koff[j] = (((ss[j] << 6) + dd[j]) << 1) ^ ((ss[j] & 7) << 4);
  }
  // PV B-frag (V^T) per-dc row offsets
  int vro[4], vsz[4];
  #pragma unroll
  for (int dc = 0; dc < 4; ++dc) {
    int d = dc * 16 + m;
    vro[dc] = d << 7;                    // d*128 bytes
    vsz[dc] = ((d >> 2) & 7) << 4;       // V^T swizzle term
  }

  const float SCL = 0.18033688011112042f;  // log2(e)/8

  for (int sidx = 0; sidx < 2; ++sidx) {
    const int qt = sidx ? (31 - pi) : pi;
    const int q0 = qt << 6;
    const int kmax = q0 + 64;
    const int nIter = kmax >> 6;
    const int qwrow = q0 + wave * 16;
    const int qbase = qwrow + g * 4;     // C-frag: row = qbase+reg, col = m

    // ---- Q A-fragments (pre-scaled; exp -> exp2) ----
    short8 aq0, aq1;
    {
      const float* qp = Qg + bhSD + (size_t)(qwrow + m) * D_HEAD + g * 8;
      float4 x0 = *(const float4*)(qp);
      float4 x1 = *(const float4*)(qp + 4);
      float4 y0 = *(const float4*)(qp + 32);
      float4 y1 = *(const float4*)(qp + 36);
      aq0[0]=(short)f2b(x0.x*SCL); aq0[1]=(short)f2b(x0.y*SCL);
      aq0[2]=(short)f2b(x0.z*SCL); aq0[3]=(short)f2b(x0.w*SCL);
      aq0[4]=(short)f2b(x1.x*SCL); aq0[5]=(short)f2b(x1.y*SCL);
      aq0[6]=(short)f2b(x1.z*SCL); aq0[7]=(short)f2b(x1.w*SCL);
      aq1[0]=(short)f2b(y0.x*SCL); aq1[1]=(short)f2b(y0.y*SCL);
      aq1[2]=(short)f2b(y0.z*SCL); aq1[3]=(short)f2b(y0.w*SCL);
      aq1[4]=(short)f2b(y1.x*SCL); aq1[5]=(short)f2b(y1.y*SCL);
      aq1[6]=(short)f2b(y1.z*SCL); aq1[7]=(short)f2b(y1.w*SCL);
    }

    // ================= Phase 1: row sums of exp =================
    float rs0 = 0.f, rs1 = 0.f, rs2 = 0.f, rs3 = 0.f;
    {  // preload tile 0 -> Kl[0]
      float4 kr[4];
      #pragma unroll
      for (int j = 0; j < 4; ++j)
        kr[j] = *(const float4*)(Kg + bhSD + (size_t)ss[j] * D_HEAD + dd[j]);
      #pragma unroll
      for (int j = 0; j < 4; ++j) {
        ushort4 kb;
        kb.x = f2b(kr[j].x); kb.y = f2b(kr[j].y);
        kb.z = f2b(kr[j].z); kb.w = f2b(kr[j].w);
        *(ushort4*)((char*)Kl[0] + koff[j]) = kb;
      }
    }
    __syncthreads();
    int cur = 0;
    for (int it = 0; it < nIter; ++it) {
      const int kc = it << 6;
      const bool pf = (it + 1 < nIter);
      float4 kr[4];
      if (pf) {  // issue next-tile loads early (hide under compute)
        #pragma unroll
        for (int j = 0; j < 4; ++j)
          kr[j] = *(const float4*)(Kg + bhSD + (size_t)(kc + 64 + ss[j]) * D_HEAD + dd[j]);
      }
      const char* KB = (const char*)Kl[cur];
      #pragma unroll
      for (int t = 0; t < 4; ++t) {
        f32x4 acc = {0.f, 0.f, 0.f, 0.f};
        const int rb = (t * 16 + m) << 7;  // row*128 bytes
        short8 b0 = *(const short8*)(KB + ((rb + g * 16) ^ swzK));
        short8 b1 = *(const short8*)(KB + ((rb + 64 + g * 16) ^ swzK));
        acc = __builtin_amdgcn_mfma_f32_16x16x32_bf16(aq0, b0, acc, 0, 0, 0);
        acc = __builtin_amdgcn_mfma_f32_16x16x32_bf16(aq1, b1, acc, 0, 0, 0);
        const int kcol = kc + t * 16 + m;
        rs0 += (kcol <= qbase + 0) ? exp2f(acc[0]) : 0.f;
        rs1 += (kcol <= qbase + 1) ? exp2f(acc[1]) : 0.f;
        rs2 += (kcol <= qbase + 2) ? exp2f(acc[2]) : 0.f;
        rs3 += (kcol <= qbase + 3) ? exp2f(acc[3]) : 0.f;
      }
      if (pf) {
        #pragma unroll
        for (int j = 0; j < 4; ++j) {
          ushort4 kb;
          kb.x = f2b(kr[j].x); kb.y = f2b(kr[j].y);
          kb.z = f2b(kr[j].z); kb.w = f2b(kr[j].w);
          *(ushort4*)((char*)Kl[cur ^ 1] + koff[j]) = kb;
        }
      }
      __syncthreads();
      cur ^= 1;
    }
    #pragma unroll
    for (int sft = 1; sft < 16; sft <<= 1) {
      rs0 += __shfl_xor(rs0, sft, 64);
      rs1 += __shfl_xor(rs1, sft, 64);
      rs2 += __shfl_xor(rs2, sft, 64);
      rs3 += __shfl_xor(rs3, sft, 64);
    }
    const float ri0 = 1.f / rs0, ri1 = 1.f / rs1, ri2 = 1.f / rs2, ri3 = 1.f / rs3;

    // ================= Phase 2: recompute, write attn, accumulate O =========
    f32x4 o0 = {0.f,0.f,0.f,0.f}, o1 = {0.f,0.f,0.f,0.f};
    f32x4 o2 = {0.f,0.f,0.f,0.f}, o3 = {0.f,0.f,0.f,0.f};
    {  // preload tile 0 -> Kl[0], Vt[0]
      float4 kr[4], vr[4];
      #pragma unroll
      for (int j = 0; j < 4; ++j) {
        kr[j] = *(const float4*)(Kg + bhSD + (size_t)ss[j] * D_HEAD + dd[j]);
        vr[j] = *(const float4*)(Vg + bhSD + (size_t)ss[j] * D_HEAD + dd[j]);
      }
      #pragma unroll
      for (int j = 0; j < 4; ++j) {
        ushort4 kb;
        kb.x = f2b(kr[j].x); kb.y = f2b(kr[j].y);
        kb.z = f2b(kr[j].z); kb.w = f2b(kr[j].w);
        *(ushort4*)((char*)Kl[0] + koff[j]) = kb;
        const int d0 = dd[j], s2 = ss[j] << 1;
        char* VB1 = (char*)Vt[0];
        *(unsigned short*)(VB1 + ((((d0+0)<<7) + s2) ^ ((((d0+0)>>2)&7)<<4))) = f2b(vr[j].x);
        *(unsigned short*)(VB1 + ((((d0+1)<<7) + s2) ^ ((((d0+1)>>2)&7)<<4))) = f2b(vr[j].y);
        *(unsigned short*)(VB1 + ((((d0+2)<<7) + s2) ^ ((((d0+2)>>2)&7)<<4))) = f2b(vr[j].z);
        *(unsigned short*)(VB1 + ((((d0+3)<<7) + s2) ^ ((((d0+3)>>2)&7)<<4))) = f2b(vr[j].w);
      }
    }
    __syncthreads();
    cur = 0;
    for (int it = 0; it < nIter; ++it) {
      const int kc = it << 6;
      const bool pf = (it + 1 < nIter);
      float4 kr[4], vr[4];
      if (pf) {
        #pragma unroll
        for (int j = 0; j < 4; ++j) {
          kr[j] = *(const float4*)(Kg + bhSD + (size_t)(kc + 64 + ss[j]) * D_HEAD + dd[j]);
          vr[j] = *(const float4*)(Vg + bhSD + (size_t)(kc + 64 + ss[j]) * D_HEAD + dd[j]);
        }
      }
      const char* KB = (const char*)Kl[cur];
      const char* VB = (const char*)Vt[cur];
      float* arow = attn + bhSS + (size_t)qbase * S_LEN + kc;
      #pragma unroll
      for (int t = 0; t < 4; ++t) {
        f32x4 acc = {0.f, 0.f, 0.f, 0.f};
        const int rb = (t * 16 + m) << 7;
        short8 b0 = *(const short8*)(KB + ((rb + g * 16) ^ swzK));
        short8 b1 = *(const short8*)(KB + ((rb + 64 + g * 16) ^ swzK));
        acc = __builtin_amdgcn_mfma_f32_16x16x32_bf16(aq0, b0, acc, 0, 0, 0);
        acc = __builtin_amdgcn_mfma_f32_16x16x32_bf16(aq1, b1, acc, 0, 0, 0);
        const int kcol = kc + t * 16 + m;
        const int tc = t * 16 + m;
        float p0 = (kcol <= qbase + 0) ? exp2f(acc[0]) * ri0 : 0.f;
        float p1 = (kcol <= qbase + 1) ? exp2f(acc[1]) * ri1 : 0.f;
        float p2 = (kcol <= qbase + 2) ? exp2f(acc[2]) * ri2 : 0.f;
        float p3 = (kcol <= qbase + 3) ? exp2f(acc[3]) * ri3 : 0.f;
        arow[0 * S_LEN + tc] = p0;
        arow[1 * S_LEN + tc] = p1;
        arow[2 * S_LEN + tc] = p2;
        arow[3 * S_LEN + tc] = p3;
        const int r0 = g * 4, c2 = tc << 1;
        *(unsigned short*)(PB + ((((r0+0)<<7) + c2) ^ (((r0+0)&7)<<4))) = f2b(p0);
        *(unsigned short*)(PB + ((((r0+1)<<7) + c2) ^ (((r0+1)&7)<<4))) = f2b(p1);
        *(unsigned short*)(PB + ((((r0+2)<<7) + c2) ^ (((r0+2)&7)<<4))) = f2b(p2);
        *(unsigned short*)(PB + ((((r0+3)<<7) + c2) ^ (((r0+3)&7)<<4))) = f2b(p3);
      }
      // PV: A = P rows (row=m), B = V^T (col=d), reduce over this tile's 64 k
      short8 pa0 = *(const short8*)(PB + (((m << 7) + g * 16) ^ swzK));
      short8 pa1 = *(const short8*)(PB + (((m << 7) + 64 + g * 16) ^ swzK));
      {
        short8 bv0 = *(const short8*)(VB + ((vro[0] + g * 16) ^ vsz[0]));
        short8 bv1 = *(const short8*)(VB + ((vro[0] + 64 + g * 16) ^ vsz[0]));
        o0 = __builtin_amdgcn_mfma_f32_16x16x32_bf16(pa0, bv0, o0, 0, 0, 0);
        o0 = __builtin_amdgcn_mfma_f32_16x16x32_bf16(pa1, bv1, o0, 0, 0, 0);
      }
      {
        short8 bv0 = *(const short8*)(VB + ((vro[1] + g * 16) ^ vsz[1]));
        short8 bv1 = *(const short8*)(VB + ((vro[1] + 64 + g * 16) ^ vsz[1]));
        o1 = __builtin_amdgcn_mfma_f32_16x16x32_bf16(pa0, bv0, o1, 0, 0, 0);
        o1 = __builtin_amdgcn_mfma_f32_16x16x32_bf16(pa1, bv1, o1, 0, 0, 0);
      }
      {
        short8 bv0 = *(const short8*)(VB + ((vro[2] + g * 16) ^ vsz[2]));
        short8 bv1 = *(const short8*)(VB + ((vro[2] + 64 + g * 16) ^ vsz[2]));
        o2 = __builtin_amdgcn_mfma_f32_16x16x32_bf16(pa0, bv0, o2, 0, 0, 0);
        o2 = __builtin_amdgcn_mfma_f32_16x16x32_bf16(pa1, bv1, o2, 0, 0, 0);
      }
      {
        short8 bv0 = *(const short8*)(VB + ((vro[3] + g * 16) ^ vsz[3]));
        short8 bv1 = *(const short8*)(VB + ((vro[3] + 64 + g * 16) ^ vsz[3]));
        o3 = __builtin_amdgcn_mfma_f32_16x16x32_bf16(pa0, bv0, o3, 0, 0, 0);
        o3 = __builtin_amdgcn_mfma_f32_16x16x32_bf16(pa1, bv1, o3, 0, 0, 0);
      }
      if (pf) {  // stage next tile into the alternate buffers
        #pragma unroll
        for (int j = 0; j < 4; ++j) {
          ushort4 kb;
          kb.x = f2b(kr[j].x); kb.y = f2b(kr[j].y);
          kb.z = f2b(kr[j].z); kb.w = f2b(kr[j].w);
          *(ushort4*)((char*)Kl[cur ^ 1] + koff[j]) = kb;
          const int d0 = dd[j], s2 = ss[j] << 1;
          char* VB1 = (char*)Vt[cur ^ 1];
          *(unsigned short*)(VB1 + ((((d0+0)<<7) + s2) ^ ((((d0+0)>>2)&7)<<4))) = f2b(vr[j].x);
          *(unsigned short*)(VB1 + ((((d0+1)<<7) + s2) ^ ((((d0+1)>>2)&7)<<4))) = f2b(vr[j].y);
          *(unsigned short*)(VB1 + ((((d0+2)<<7) + s2) ^ ((((d0+2)>>2)&7)<<4))) = f2b(vr[j].z);
          *(unsigned short*)(VB1 + ((((d0+3)<<7) + s2) ^ ((((d0+3)>>2)&7)<<4))) = f2b(vr[j].w);
        }
      }
      __syncthreads();
      cur ^= 1;
    }

    // ---- store O ----
    #pragma unroll
    for (int reg = 0; reg < 4; ++reg) {
      size_t rb = bhSD + (size_t)(qbase + reg) * D_HEAD + m;
      outp[rb +  0] = o0[reg];
      outp[rb + 16] = o1[reg];
      outp[rb + 32] = o2[reg];
      outp[rb + 48] = o3[reg];
    }

    // ---- zero-fill fully-masked columns [kmax, S) for this strip's 64 rows ----
    const int ncols = S_LEN - kmax;
    if (ncols > 0) {
      const float4 z = {0.f, 0.f, 0.f, 0.f};
      const int nvec = ncols >> 2;
      for (int r = 0; r < 64; ++r) {
        float4* rp = (float4*)(attn + bhSS + (size_t)(q0 + r) * S_LEN + kmax);
        for (int i = tid; i < nvec; i += 256) rp[i] = z;
      }
    }
  }
}

extern "C" void kernel_launch(void* const* d_in, const int* in_sizes, int n_in,
                              void* d_out, int out_size, void* d_ws, size_t ws_size,
                              hipStream_t stream) {
  (void)in_sizes; (void)n_in; (void)d_ws; (void)ws_size; (void)out_size;
  const float* q = (const float*)d_in[0];
  const float* k = (const float*)d_in[1];
  const float* v = (const float*)d_in[2];
  float* attn = (float*)d_out;
  float* outp = attn + (size_t)2 * 16 * 2048 * 2048;
  dim3 grid(32 * 16);   // 32 bh x 16 strip-pairs, uniform cost per block
  dim3 block(256);
  sdpa_causal_kernel<<<grid, block, 0, stream>>>(q, k, v, attn, outp);
}